// Round 5
// baseline (720.540 us; speedup 1.0000x reference)
//
#include <hip/hip_runtime.h>

#define N_NODES 50000
#define N_EDGES 800000
#define FEAT 64
#define HID 128
#define N_TYPES 4
#define N_REL 3
#define N_LAYERS 2
#define LN_EPS 1e-5f
#define NGROUPS 3125  // 50000 / 16, exact
#define NB 196        // ceil(50000/256) scan blocks
#define WT_STRIDE 136 // 128+8: 16B-aligned rows, 2-way (free) bank aliasing

typedef __attribute__((ext_vector_type(8))) short bf16x8;
typedef __attribute__((ext_vector_type(4))) float f32x4;

// float -> bf16 bits, round-to-nearest-even (finite inputs)
static __device__ inline unsigned short f2bf(float f) {
    unsigned int u = __float_as_uint(f);
    return (unsigned short)((u + 0x7fffu + ((u >> 16) & 1u)) >> 16);
}
static __device__ inline unsigned int packbf2(float lo, float hi) {
    return (unsigned int)f2bf(lo) | ((unsigned int)f2bf(hi) << 16);
}

// ---------------------------------------------------------------------------
// CSR build by destination
__global__ void count_kernel(const int* __restrict__ dst, int* __restrict__ cnt) {
    int e = blockIdx.x * blockDim.x + threadIdx.x;
    if (e < N_EDGES) atomicAdd(&cnt[dst[e]], 1);
}

__global__ __launch_bounds__(256) void scan1_kernel(const int* __restrict__ cnt,
                                                    int* __restrict__ bsum) {
    __shared__ int sh[256];
    int i = blockIdx.x * 256 + threadIdx.x;
    sh[threadIdx.x] = (i < N_NODES) ? cnt[i] : 0;
    __syncthreads();
    for (int d = 128; d; d >>= 1) {
        if (threadIdx.x < d) sh[threadIdx.x] += sh[threadIdx.x + d];
        __syncthreads();
    }
    if (threadIdx.x == 0) bsum[blockIdx.x] = sh[0];
}

__global__ __launch_bounds__(256) void scan2_kernel(const int* __restrict__ bsum,
                                                    int* __restrict__ boff,
                                                    int* __restrict__ off) {
    __shared__ int sh[256];
    int t = threadIdx.x;
    int v = (t < NB) ? bsum[t] : 0;
    sh[t] = v;
    __syncthreads();
    int acc = v;
    for (int d = 1; d < 256; d <<= 1) {
        int u = (t >= d) ? sh[t - d] : 0;
        __syncthreads();
        acc += u;
        sh[t] = acc;
        __syncthreads();
    }
    if (t < NB) boff[t] = acc - v;  // exclusive
    if (t == 0) off[N_NODES] = N_EDGES;
}

__global__ __launch_bounds__(256) void scan3_kernel(const int* __restrict__ cnt,
                                                    const int* __restrict__ boff,
                                                    int* __restrict__ off,
                                                    int* __restrict__ cursor) {
    __shared__ int sh[256];
    int i = blockIdx.x * 256 + threadIdx.x;
    int v = (i < N_NODES) ? cnt[i] : 0;
    sh[threadIdx.x] = v;
    __syncthreads();
    int acc = v;
    for (int d = 1; d < 256; d <<= 1) {
        int u = (threadIdx.x >= d) ? sh[threadIdx.x - d] : 0;
        __syncthreads();
        acc += u;
        sh[threadIdx.x] = acc;
        __syncthreads();
    }
    if (i < N_NODES) {
        int excl = boff[blockIdx.x] + acc - v;
        off[i] = excl;
        cursor[i] = excl;
    }
}

__global__ void fill_kernel(const int* __restrict__ src, const int* __restrict__ dst,
                            const int* __restrict__ et, int* __restrict__ cursor,
                            int* __restrict__ payload) {
    int e = blockIdx.x * blockDim.x + threadIdx.x;
    if (e < N_EDGES) {
        int pos = atomicAdd(&cursor[dst[e]], 1);
        payload[pos] = src[e] | (et[e] << 16);  // src < 65536, et < 3
    }
}

// ---------------------------------------------------------------------------
// Encoder collapses to a 400-entry table: combo = z*4 + type.
__global__ __launch_bounds__(128) void enc_table_kernel(const float* __restrict__ z_embed,
                                                        const float* __restrict__ w1,
                                                        const float* __restrict__ b1,
                                                        const float* __restrict__ w2,
                                                        const float* __restrict__ b2,
                                                        unsigned short* __restrict__ xt) {
    int zi = blockIdx.x >> 2;
    int t = blockIdx.x & 3;
    int j = threadIdx.x;
    __shared__ float h[HID];
    float acc = b1[t * HID + j];
#pragma unroll 8
    for (int k = 0; k < FEAT; ++k)
        acc = fmaf(z_embed[zi * FEAT + k], w1[((size_t)t * FEAT + k) * HID + j], acc);
    h[j] = fmaxf(acc, 0.0f);
    __syncthreads();
    float acc2 = b2[t * HID + j];
#pragma unroll 8
    for (int k = 0; k < HID; ++k)
        acc2 = fmaf(h[k], w2[(size_t)t * HID * HID + k * HID + j], acc2);
    xt[blockIdx.x * HID + j] = f2bf(acc2);
}

__global__ __launch_bounds__(256) void node_fill_kernel(const int* __restrict__ z,
                                                        const int* __restrict__ nt,
                                                        const unsigned int* __restrict__ xtu,
                                                        unsigned int* __restrict__ xbu) {
    int idx = blockIdx.x * blockDim.x + threadIdx.x;
    int node = idx >> 6;
    if (node >= N_NODES) return;
    int lane = idx & 63;
    int combo = z[node] * 4 + nt[node];
    xbu[node * 64 + lane] = xtu[combo * 64 + lane];
}

// ---------------------------------------------------------------------------
// One wave per dst node: s_r[n] = sum of xb[src] over incoming edges of type r.
__global__ __launch_bounds__(256) void gather3_kernel(const int* __restrict__ off,
                                                      const int* __restrict__ payload,
                                                      const unsigned int* __restrict__ xbu,
                                                      unsigned int* __restrict__ s0,
                                                      unsigned int* __restrict__ s1,
                                                      unsigned int* __restrict__ s2) {
    int node = (blockIdx.x * blockDim.x + threadIdx.x) >> 6;
    if (node >= N_NODES) return;
    int lane = threadIdx.x & 63;
    int e0 = off[node], e1 = off[node + 1];
    float a00 = 0.f, a01 = 0.f, a10 = 0.f, a11 = 0.f, a20 = 0.f, a21 = 0.f;
    int e = e0;
    for (; e + 2 <= e1; e += 2) {
        int pA = payload[e];
        int pB = payload[e + 1];
        unsigned int vA = xbu[(pA & 0xffff) * 64 + lane];
        unsigned int vB = xbu[(pB & 0xffff) * 64 + lane];
        float loA = __uint_as_float(vA << 16), hiA = __uint_as_float(vA & 0xffff0000u);
        float loB = __uint_as_float(vB << 16), hiB = __uint_as_float(vB & 0xffff0000u);
        int rA = pA >> 16, rB = pB >> 16;  // wave-uniform branches
        if (rA == 0) { a00 += loA; a01 += hiA; }
        else if (rA == 1) { a10 += loA; a11 += hiA; }
        else { a20 += loA; a21 += hiA; }
        if (rB == 0) { a00 += loB; a01 += hiB; }
        else if (rB == 1) { a10 += loB; a11 += hiB; }
        else { a20 += loB; a21 += hiB; }
    }
    if (e < e1) {
        int p = payload[e];
        unsigned int v = xbu[(p & 0xffff) * 64 + lane];
        float lo = __uint_as_float(v << 16), hi = __uint_as_float(v & 0xffff0000u);
        int r = p >> 16;
        if (r == 0) { a00 += lo; a01 += hi; }
        else if (r == 1) { a10 += lo; a11 += hi; }
        else { a20 += lo; a21 += hi; }
    }
    int o = node * 64 + lane;
    s0[o] = packbf2(a00, a01);
    s1[o] = packbf2(a10, a11);
    s2[o] = packbf2(a20, a21);
}

// ---------------------------------------------------------------------------
// Fused layer, wave-private groups: each wave owns whole 16-node groups and
// computes all 8 column tiles itself -> LN reduce is in-wave (shfl only),
// zero barriers in the main loop. All 4 weight matrices bf16-transposed in
// LDS (4 x 128 x 136 x 2B = 136 KB). A-fragments double-buffered in regs.
// MFMA layouts (verified m89/m91): A[m=lane&15][k=quad*8+j], B[n][k] same,
// C/D col=lane&15, row=quad*4+reg.
__global__ __launch_bounds__(512, 1) void fused_layer_kernel(
    const unsigned short* __restrict__ s0, const unsigned short* __restrict__ s1,
    const unsigned short* __restrict__ s2, unsigned short* __restrict__ xb,
    const float* __restrict__ W0, const float* __restrict__ W1,
    const float* __restrict__ W2, const float* __restrict__ Wl,
    const float* __restrict__ lb, const int* __restrict__ cnt,
    const float* __restrict__ lng, const float* __restrict__ lnb,
    float* __restrict__ pooled, int do_pool) {
    __shared__ unsigned short Wt[4 * HID * WT_STRIDE];  // 139264 B
    __shared__ float pooled_sh[HID];

    if (threadIdx.x < HID) pooled_sh[threadIdx.x] = 0.0f;

    // stage: Wt[mat][col*WT_STRIDE + k] = bf16(Wmat[k*HID + col])
    const float* Wsrc[4] = {W0, W1, W2, Wl};
    for (int i = threadIdx.x; i < 4 * HID * HID; i += 512) {
        int mat = i >> 14;          // /16384
        int idx = i & 16383;
        int k = idx >> 7, col = idx & 127;
        Wt[mat * HID * WT_STRIDE + col * WT_STRIDE + k] = f2bf(Wsrc[mat][idx]);
    }
    __syncthreads();

    int wave = threadIdx.x >> 6;
    int lane = threadIdx.x & 63;
    int m = lane & 15;
    int quad = lane >> 4;

    // per-column constants for this lane's 8 column slots (col = ht*16+m)
    float bv[8], gc[8], bc[8];
#pragma unroll
    for (int ht = 0; ht < 8; ++ht) {
        int col = ht * 16 + m;
        bv[ht] = lb[col];
        gc[ht] = lng[col];
        bc[ht] = lnb[col];
    }
    float pacc[8] = {0, 0, 0, 0, 0, 0, 0, 0};

    const int stride = gridDim.x * 8;
    int g = blockIdx.x * 8 + wave;

    bf16x8 c0[4], c1[4], c2[4], cx[4];  // current A frags
    bf16x8 n0[4], n1[4], n2[4], nx[4];  // next A frags

    if (g < NGROUPS) {
        int ro = (g * 16 + m) * HID + quad * 8;
#pragma unroll
        for (int kc = 0; kc < 4; ++kc) {
            c0[kc] = *(const bf16x8*)(s0 + ro + kc * 32);
            c1[kc] = *(const bf16x8*)(s1 + ro + kc * 32);
            c2[kc] = *(const bf16x8*)(s2 + ro + kc * 32);
            cx[kc] = *(const bf16x8*)(xb + ro + kc * 32);
        }
    }

    for (; g < NGROUPS; g += stride) {
        int gn = g + stride;
        if (gn < NGROUPS) {  // prefetch next group's A fragments
            int ro = (gn * 16 + m) * HID + quad * 8;
#pragma unroll
            for (int kc = 0; kc < 4; ++kc) {
                n0[kc] = *(const bf16x8*)(s0 + ro + kc * 32);
                n1[kc] = *(const bf16x8*)(s1 + ro + kc * 32);
                n2[kc] = *(const bf16x8*)(s2 + ro + kc * 32);
                nx[kc] = *(const bf16x8*)(xb + ro + kc * 32);
            }
        }
        int node0 = g * 16;
        float inv[4];
#pragma unroll
        for (int r = 0; r < 4; ++r)
            inv[r] = 1.0f / (float)max(cnt[node0 + quad * 4 + r], 1);

        float v[8][4];
#pragma unroll
        for (int ht = 0; ht < 8; ++ht) {
            f32x4 accA = {0.f, 0.f, 0.f, 0.f};
            f32x4 accY = {0.f, 0.f, 0.f, 0.f};
            int wbase = (ht * 16 + m) * WT_STRIDE + quad * 8;
#pragma unroll
            for (int kc = 0; kc < 4; ++kc) {
                bf16x8 b0 = *(const bf16x8*)(Wt + 0 * HID * WT_STRIDE + wbase + kc * 32);
                bf16x8 b1 = *(const bf16x8*)(Wt + 1 * HID * WT_STRIDE + wbase + kc * 32);
                bf16x8 b2 = *(const bf16x8*)(Wt + 2 * HID * WT_STRIDE + wbase + kc * 32);
                bf16x8 bl = *(const bf16x8*)(Wt + 3 * HID * WT_STRIDE + wbase + kc * 32);
                accA = __builtin_amdgcn_mfma_f32_16x16x32_bf16(c0[kc], b0, accA, 0, 0, 0);
                accA = __builtin_amdgcn_mfma_f32_16x16x32_bf16(c1[kc], b1, accA, 0, 0, 0);
                accA = __builtin_amdgcn_mfma_f32_16x16x32_bf16(c2[kc], b2, accA, 0, 0, 0);
                accY = __builtin_amdgcn_mfma_f32_16x16x32_bf16(cx[kc], bl, accY, 0, 0, 0);
            }
#pragma unroll
            for (int r = 0; r < 4; ++r) v[ht][r] = accY[r] + bv[ht] + accA[r] * inv[r];
        }
        // in-wave LN per row (rows quad*4+r live in this 16-lane group)
#pragma unroll
        for (int r = 0; r < 4; ++r) {
            float s = 0.f, q = 0.f;
#pragma unroll
            for (int ht = 0; ht < 8; ++ht) {
                s += v[ht][r];
                q += v[ht][r] * v[ht][r];
            }
#pragma unroll
            for (int mk = 1; mk < 16; mk <<= 1) {
                s += __shfl_xor(s, mk);
                q += __shfl_xor(q, mk);
            }
            float mu = s * (1.0f / HID);
            float var = q * (1.0f / HID) - mu * mu;
            float rstd = rsqrtf(var + LN_EPS);
            int row = node0 + quad * 4 + r;
#pragma unroll
            for (int ht = 0; ht < 8; ++ht) {
                float outv = (v[ht][r] - mu) * rstd * gc[ht] + bc[ht];
                if (do_pool) pacc[ht] += outv;
                else xb[row * HID + ht * 16 + m] = f2bf(outv);
            }
        }
        // rotate buffers
#pragma unroll
        for (int kc = 0; kc < 4; ++kc) {
            c0[kc] = n0[kc]; c1[kc] = n1[kc]; c2[kc] = n2[kc]; cx[kc] = nx[kc];
        }
    }

    if (do_pool) {
#pragma unroll
        for (int ht = 0; ht < 8; ++ht) {
            float t = pacc[ht];
            t += __shfl_xor(t, 16);
            t += __shfl_xor(t, 32);
            if (quad == 0) atomicAdd(&pooled_sh[ht * 16 + m], t);
        }
        __syncthreads();
        if (threadIdx.x < HID) atomicAdd(&pooled[threadIdx.x], pooled_sh[threadIdx.x]);
    }
}

// ---------------------------------------------------------------------------
__global__ void final_kernel(const float* __restrict__ pooled, const float* __restrict__ reg_w,
                             const float* __restrict__ reg_b, float* __restrict__ out) {
    int lane = threadIdx.x;  // 64
    float s = pooled[lane] * reg_w[lane] + pooled[64 + lane] * reg_w[64 + lane];
#pragma unroll
    for (int o = 32; o; o >>= 1) s += __shfl_down(s, o);
    if (lane == 0) out[0] = s * (1.0f / N_NODES) + reg_b[0];
}

// ---------------------------------------------------------------------------
extern "C" void kernel_launch(void* const* d_in, const int* in_sizes, int n_in,
                              void* d_out, int out_size, void* d_ws, size_t ws_size,
                              hipStream_t stream) {
    const int* z = (const int*)d_in[0];
    const int* nt = (const int*)d_in[1];
    const int* ei = (const int*)d_in[2];
    const int* et = (const int*)d_in[3];
    const float* z_embed = (const float*)d_in[4];
    const float* enc_w1 = (const float*)d_in[5];
    const float* enc_b1 = (const float*)d_in[6];
    const float* enc_w2 = (const float*)d_in[7];
    const float* enc_b2 = (const float*)d_in[8];
    const float* lin_w = (const float*)d_in[9];
    const float* lin_b = (const float*)d_in[10];
    const float* rel_w = (const float*)d_in[11];
    const float* ln_g = (const float*)d_in[12];
    const float* ln_b = (const float*)d_in[13];
    const float* reg_w = (const float*)d_in[14];
    const float* reg_b = (const float*)d_in[15];
    float* out = (float*)d_out;

    const size_t NHb = (size_t)N_NODES * HID;
    char* p = (char*)d_ws;
    unsigned short* xb = (unsigned short*)p;  p += NHb * 2;
    unsigned short* s0 = (unsigned short*)p;  p += NHb * 2;
    unsigned short* s1 = (unsigned short*)p;  p += NHb * 2;
    unsigned short* s2 = (unsigned short*)p;  p += NHb * 2;
    unsigned short* xt = (unsigned short*)p;  p += 400 * HID * 2;
    float* pooled = (float*)p;                p += HID * 4;
    int* cnt = (int*)p;                       p += N_NODES * 4;
    int* off = (int*)p;                       p += (N_NODES + 1) * 4;
    int* cursor = (int*)p;                    p += N_NODES * 4;
    int* bsum = (int*)p;                      p += NB * 4;
    int* boff = (int*)p;                      p += NB * 4;
    int* payload = (int*)p;                   p += N_EDGES * 4;

    const int* src = ei;
    const int* dst = ei + N_EDGES;

    hipMemsetAsync(cnt, 0, N_NODES * sizeof(int), stream);
    hipMemsetAsync(pooled, 0, HID * sizeof(float), stream);
    count_kernel<<<(N_EDGES + 255) / 256, 256, 0, stream>>>(dst, cnt);
    scan1_kernel<<<NB, 256, 0, stream>>>(cnt, bsum);
    scan2_kernel<<<1, 256, 0, stream>>>(bsum, boff, off);
    scan3_kernel<<<NB, 256, 0, stream>>>(cnt, boff, off, cursor);
    fill_kernel<<<(N_EDGES + 255) / 256, 256, 0, stream>>>(src, dst, et, cursor, payload);

    enc_table_kernel<<<400, 128, 0, stream>>>(z_embed, enc_w1, enc_b1, enc_w2, enc_b2, xt);
    node_fill_kernel<<<(N_NODES * 64 + 255) / 256, 256, 0, stream>>>(
        z, nt, (const unsigned int*)xt, (unsigned int*)xb);

    const int nwb = (N_NODES * 64 + 255) / 256;  // one wave per node
    for (int l = 0; l < N_LAYERS; ++l) {
        gather3_kernel<<<nwb, 256, 0, stream>>>(off, payload, (const unsigned int*)xb,
                                                (unsigned int*)s0, (unsigned int*)s1,
                                                (unsigned int*)s2);
        const float* Wl = rel_w + (size_t)l * N_REL * HID * HID;
        fused_layer_kernel<<<196, 512, 0, stream>>>(
            s0, s1, s2, xb, Wl, Wl + HID * HID, Wl + 2 * HID * HID,
            lin_w + (size_t)l * HID * HID, lin_b + l * HID, cnt,
            ln_g + l * HID, ln_b + l * HID, pooled, l == N_LAYERS - 1 ? 1 : 0);
    }

    final_kernel<<<1, 64, 0, stream>>>(pooled, reg_w, reg_b, out);
}